// Round 2
// baseline (715.562 us; speedup 1.0000x reference)
//
#include <hip/hip_runtime.h>
#include <hip/hip_bf16.h>
#include <hip/hip_fp16.h>
#include <hip/hip_cooperative_groups.h>

namespace cg = cooperative_groups;

#define NRANGE   8       // node ranges (LDS accumulator tiles)
#define RLEN_MAX 12800   // floats per range in LDS (51.2 KB)
#define N_XCD    8       // MI355X XCDs; blockIdx%8 ~ XCD round-robin
#define SL_XCD   8       // slices per XCD
#define SLICES   64      // total edge slices
#define WIN_E    2048    // edges per etrec window (512 thr * 4)
#define FB       512     // fused grid blocks (2/CU co-resident)
#define FT       512     // fused block threads

typedef float vfloat4 __attribute__((ext_vector_type(4)));
typedef unsigned long long u64;

__device__ __forceinline__ float edge_e(float2 ns, float2 nd, float Li,
                                        float ci, float Ai, float dt) {
    const float delta = ns.x - nd.x;
    if (delta <= 0.0f) return 0.0f;
    const float x = (delta / Li) * ci;
    const float ec = cbrtf(x) * Ai * dt;
    const float comb = (nd.y * ns.y) / (nd.y + ns.y);
    return fminf(ec, delta * comb);
}

// record = s(17b) | d(17b)<<17 | f16(e)<<34  (only nonzero edges recorded)
__device__ __forceinline__ u64 make_rec(int s, int d, float e) {
    return (u64)(unsigned)s | ((u64)(unsigned)d << 17)
         | ((u64)__half_as_ushort(__float2half_rn(e)) << 34);
}

__device__ __forceinline__ void acc_rec(u64 rec, float* __restrict__ lds,
                                        int base, int rlen) {
    const int   sv = (int)(rec & 0x1FFFF);
    const int   dv = (int)((rec >> 17) & 0x1FFFF);
    const float e  = __half2float(__ushort_as_half((unsigned short)(rec >> 34)));
    const int ls = sv - base; if ((unsigned)ls < (unsigned)rlen) atomicAdd(&lds[ls], -e);
    const int ld = dv - base; if ((unsigned)ld < (unsigned)rlen) atomicAdd(&lds[ld],  e);
}

// ---------------------------------------------------------------------------
// FUSED cooperative pipeline: pack -> etrec -> accrec -> reduce in ONE
// dispatch, grid.sync() between phases. R2 experiment: R0/R1 showed every
// kernel-internal change is neutral while ~100us of the 247us total is
// unexplained by per-kernel math (etrec 82 + accrec ~30 + reduce ~15 + pack
// ~5). Theory: inter-dispatch bubbles/launch overhead. Phase code is kept
// identical to the proven R0 kernels. 512x512 = 2 blocks/CU co-resident;
// etrec is request-throughput-bound (3.8cy/gather/CU), and 16 waves x ~13
// in-flight loads > latency-hiding requirement, so its 82us floor should
// survive the occupancy drop.
// ---------------------------------------------------------------------------
__global__ void __launch_bounds__(FT, 4)
fused_kernel(const float* __restrict__ T, const float* __restrict__ cp,
             const float* __restrict__ L, const float* __restrict__ cond,
             const float* __restrict__ A, const float* __restrict__ time_step,
             const int* __restrict__ src, const int* __restrict__ dst,
             float2* __restrict__ nodes, u64* __restrict__ recs,
             int* __restrict__ tails, float* __restrict__ copies,
             float* __restrict__ out,
             int n_nodes, int n_edges, int wps, int cap, int R) {
    cg::grid_group grid = cg::this_grid();
    __shared__ union SH {
        struct { u64 srec[8 * 256]; int wcnt[8]; int wbase[8]; int sbase; } e;
        float acc[RLEN_MAX];
    } sh;

    const int b   = blockIdx.x;
    const int tid = threadIdx.x;

    // ---- phase 1: pack (T,cp)->float2 nodes; zero slice tails ----
    for (int i = b * FT + tid; i < n_nodes; i += FB * FT)
        nodes[i] = make_float2(T[i], cp[i]);
    if (b == 0 && tid < SLICES) tails[tid] = 0;
    __threadfence();
    grid.sync();

    // ---- phase 2: etrec, grid-stride over windows, XCD-affine (vb%8==b%8) ----
    {
        const float dt  = time_step[0];
        const int wave  = tid >> 6;
        const int lane  = tid & 63;
        const int wpx   = SL_XCD * wps;
        const int nwin  = SLICES * wps;
        for (int vb = b; vb < nwin; vb += FB) {
            const int w  = (vb % N_XCD) * wpx + vb / N_XCD;
            const int s  = w / wps;
            const int e0 = w * WIN_E;
            int my_off = 0;
            const bool active = (e0 < n_edges);

            if (active) {
                float ev[4]; int sv[4]; int dv[4];
                if (e0 + WIN_E <= n_edges) {              // full window: vec4
                    const int kk = (e0 >> 2) + tid;       // e0 % 4 == 0
                    const int4    si = ((const int4*)src)[kk];
                    const int4    di = ((const int4*)dst)[kk];
                    const vfloat4 Lv = __builtin_nontemporal_load(&((const vfloat4*)L)[kk]);
                    const vfloat4 cv = __builtin_nontemporal_load(&((const vfloat4*)cond)[kk]);
                    const vfloat4 Av = __builtin_nontemporal_load(&((const vfloat4*)A)[kk]);
                    const float2 ns0 = nodes[si.x], ns1 = nodes[si.y], ns2 = nodes[si.z], ns3 = nodes[si.w];
                    const float2 nd0 = nodes[di.x], nd1 = nodes[di.y], nd2 = nodes[di.z], nd3 = nodes[di.w];
                    ev[0] = edge_e(ns0, nd0, Lv.x, cv.x, Av.x, dt);
                    ev[1] = edge_e(ns1, nd1, Lv.y, cv.y, Av.y, dt);
                    ev[2] = edge_e(ns2, nd2, Lv.z, cv.z, Av.z, dt);
                    ev[3] = edge_e(ns3, nd3, Lv.w, cv.w, Av.w, dt);
                    sv[0] = si.x; sv[1] = si.y; sv[2] = si.z; sv[3] = si.w;
                    dv[0] = di.x; dv[1] = di.y; dv[2] = di.z; dv[3] = di.w;
                } else {                                  // partial last window
#pragma unroll
                    for (int j = 0; j < 4; ++j) {
                        const int i = e0 + 4 * tid + j;
                        float e = 0.0f; int a = 0, b2 = 0;
                        if (i < n_edges) {
                            a = src[i]; b2 = dst[i];
                            e = edge_e(nodes[a], nodes[b2], L[i], cond[i], A[i], dt);
                        }
                        ev[j] = e; sv[j] = a; dv[j] = b2;
                    }
                }
#pragma unroll
                for (int j = 0; j < 4; ++j) {
                    const u64 mask = __ballot(ev[j] > 0.0f);
                    if (ev[j] > 0.0f) {
                        const int pos = my_off + __popcll(mask & ((1ull << lane) - 1ull));
                        sh.e.srec[(wave << 8) + pos] = make_rec(sv[j], dv[j], ev[j]);
                    }
                    my_off += (int)__popcll(mask);
                }
            }

            if (lane == 0) sh.e.wcnt[wave] = my_off;
            __syncthreads();
            if (tid == 0) {
                int tot = 0;
#pragma unroll
                for (int i = 0; i < 8; ++i) { sh.e.wbase[i] = tot; tot += sh.e.wcnt[i]; }
                sh.e.sbase = (tot > 0) ? atomicAdd(&tails[s], tot) : 0;  // ONE atomic/window
            }
            __syncthreads();

            if (active) {
                const int c  = sh.e.wcnt[wave];
                const int gb = sh.e.sbase + sh.e.wbase[wave];
                u64* __restrict__ dp = recs + (size_t)s * cap;
                for (int t = lane; t < c; t += 64) {
                    const int p = gb + t;
                    if (p < cap) dp[p] = sh.e.srec[(wave << 8) + t];
                }
            }
            __syncthreads();                              // srec reuse next window
        }
    }
    __threadfence();
    grid.sync();

    // ---- phase 3: accrec, b == (xcd, slice, range); exactly FB=512 blocks ----
    {
        const int xcd  = b % N_XCD;
        const int j    = b / N_XCD;
        const int r    = j % NRANGE;
        const int sl   = xcd * SL_XCD + j / NRANGE;
        const int base = r * R;
        const int rlen = min(R, n_nodes - base);
        if (rlen > 0) {                                   // no early return: grid.sync below
            for (int t = tid; t < rlen; t += FT) sh.acc[t] = 0.0f;
            __syncthreads();

            const int cnt = min(tails[sl], cap);
            const u64* __restrict__ g = recs + (size_t)sl * cap;
            const int npair = cnt >> 1;
            const ulonglong2* __restrict__ g2 = (const ulonglong2*)g;
            for (int t = tid; t < npair; t += 2 * FT) {
                const int t2 = t + FT;
                const bool h2 = (t2 < npair);
                const ulonglong2 r0 = g2[t];
                ulonglong2 r1;
                if (h2) r1 = g2[t2];
                acc_rec(r0.x, sh.acc, base, rlen);
                acc_rec(r0.y, sh.acc, base, rlen);
                if (h2) { acc_rec(r1.x, sh.acc, base, rlen); acc_rec(r1.y, sh.acc, base, rlen); }
            }
            for (int t = (npair << 1) + tid; t < cnt; t += FT)
                acc_rec(g[t], sh.acc, base, rlen);
            __syncthreads();

            float* __restrict__ cpy = copies + (size_t)sl * n_nodes + base;
            for (int t = tid; t < rlen; t += FT) cpy[t] = sh.acc[t];
        }
    }
    __threadfence();
    grid.sync();

    // ---- phase 4: reduce 64 partial streams -> out (plain float4 stores) ----
    {
        const int nvec = n_nodes >> 2;
        for (int k = b * FT + tid; k <= nvec; k += FB * FT) {
            if (k < nvec) {
                vfloat4 v = {0.f, 0.f, 0.f, 0.f};
#pragma unroll 8
                for (int s2 = 0; s2 < SLICES; ++s2)
                    v += ((const vfloat4*)(copies + (size_t)s2 * n_nodes))[k];
                ((vfloat4*)out)[k] = v;
            } else {
                for (int i = nvec << 2; i < n_nodes; ++i) {
                    float v = 0.0f;
                    for (int s2 = 0; s2 < SLICES; ++s2) v += copies[(size_t)s2 * n_nodes + i];
                    out[i] = v;
                }
            }
        }
    }
}

// ---------------------------------------------------------------------------
// Fallback multi-dispatch path (used if cooperative launch is rejected) —
// byte-identical to the proven R0 pipeline (247us).
// ---------------------------------------------------------------------------
__global__ void __launch_bounds__(256)
pack_nodes_kernel(const float* __restrict__ T, const float* __restrict__ cp,
                  float2* __restrict__ nodes, int* __restrict__ tails, int n) {
    int i = blockIdx.x * blockDim.x + threadIdx.x;
    if (i < n) nodes[i] = make_float2(T[i], cp[i]);
    if (blockIdx.x == 0 && threadIdx.x < SLICES) tails[threadIdx.x] = 0;
}

__global__ void __launch_bounds__(512)
etrec_kernel(const float2* __restrict__ nodes,
             const float* __restrict__ L,
             const float* __restrict__ cond,
             const float* __restrict__ A,
             const float* __restrict__ time_step,
             const int* __restrict__ src,
             const int* __restrict__ dst,
             u64* __restrict__ recs, int* __restrict__ tails,
             int n_edges, int wps, int cap) {
    __shared__ u64 srec[8 * 256];
    __shared__ int wcnt[8];
    __shared__ int wbase[8];
    __shared__ int sbase;

    const int wpx  = SL_XCD * wps;
    const int w    = (blockIdx.x % N_XCD) * wpx + blockIdx.x / N_XCD;
    const int s    = w / wps;
    const int e0   = w * WIN_E;
    const int wave = threadIdx.x >> 6;
    const int lane = threadIdx.x & 63;

    int my_off = 0;
    const bool active = (e0 < n_edges);

    if (active) {
        const float dt = time_step[0];
        float ev[4]; int sv[4]; int dv[4];
        if (e0 + WIN_E <= n_edges) {
            const int kk = (e0 >> 2) + threadIdx.x;
            const int4    si = ((const int4*)src)[kk];
            const int4    di = ((const int4*)dst)[kk];
            const vfloat4 Lv = __builtin_nontemporal_load(&((const vfloat4*)L)[kk]);
            const vfloat4 cv = __builtin_nontemporal_load(&((const vfloat4*)cond)[kk]);
            const vfloat4 Av = __builtin_nontemporal_load(&((const vfloat4*)A)[kk]);
            const float2 ns0 = nodes[si.x], ns1 = nodes[si.y], ns2 = nodes[si.z], ns3 = nodes[si.w];
            const float2 nd0 = nodes[di.x], nd1 = nodes[di.y], nd2 = nodes[di.z], nd3 = nodes[di.w];
            ev[0] = edge_e(ns0, nd0, Lv.x, cv.x, Av.x, dt);
            ev[1] = edge_e(ns1, nd1, Lv.y, cv.y, Av.y, dt);
            ev[2] = edge_e(ns2, nd2, Lv.z, cv.z, Av.z, dt);
            ev[3] = edge_e(ns3, nd3, Lv.w, cv.w, Av.w, dt);
            sv[0] = si.x; sv[1] = si.y; sv[2] = si.z; sv[3] = si.w;
            dv[0] = di.x; dv[1] = di.y; dv[2] = di.z; dv[3] = di.w;
        } else {
#pragma unroll
            for (int j = 0; j < 4; ++j) {
                const int i = e0 + 4 * (int)threadIdx.x + j;
                float e = 0.0f; int a = 0, b2 = 0;
                if (i < n_edges) {
                    a = src[i]; b2 = dst[i];
                    e = edge_e(nodes[a], nodes[b2], L[i], cond[i], A[i], dt);
                }
                ev[j] = e; sv[j] = a; dv[j] = b2;
            }
        }
#pragma unroll
        for (int j = 0; j < 4; ++j) {
            const u64 mask = __ballot(ev[j] > 0.0f);
            if (ev[j] > 0.0f) {
                const int pos = my_off + __popcll(mask & ((1ull << lane) - 1ull));
                srec[(wave << 8) + pos] = make_rec(sv[j], dv[j], ev[j]);
            }
            my_off += (int)__popcll(mask);
        }
    }

    if (lane == 0) wcnt[wave] = my_off;
    __syncthreads();
    if (threadIdx.x == 0) {
        int tot = 0;
#pragma unroll
        for (int i = 0; i < 8; ++i) { wbase[i] = tot; tot += wcnt[i]; }
        sbase = (tot > 0) ? atomicAdd(&tails[s], tot) : 0;
    }
    __syncthreads();

    if (active) {
        const int c  = wcnt[wave];
        const int gb = sbase + wbase[wave];
        u64* __restrict__ dp = recs + (size_t)s * cap;
        for (int t = lane; t < c; t += 64) {
            const int p = gb + t;
            if (p < cap) dp[p] = srec[(wave << 8) + t];
        }
    }
}

__global__ void __launch_bounds__(512)
accrec_kernel(const u64* __restrict__ recs,
              const int* __restrict__ tails,
              float* __restrict__ copies,
              int n_nodes, int R, int cap) {
    __shared__ float lds[RLEN_MAX];
    const int xcd = blockIdx.x % N_XCD;
    const int j   = blockIdx.x / N_XCD;
    const int r   = j % NRANGE;
    const int b   = xcd * SL_XCD + j / NRANGE;
    const int base = r * R;
    const int rlen = min(R, n_nodes - base);
    if (rlen <= 0) return;

    for (int t = threadIdx.x; t < rlen; t += 512) lds[t] = 0.0f;
    __syncthreads();

    const int cnt = min(tails[b], cap);
    const u64* __restrict__ g = recs + (size_t)b * cap;
    const int npair = cnt >> 1;
    const ulonglong2* __restrict__ g2 = (const ulonglong2*)g;
    for (int t = threadIdx.x; t < npair; t += 1024) {
        const int t2 = t + 512;
        const bool h2 = (t2 < npair);
        const ulonglong2 r0 = g2[t];
        ulonglong2 r1;
        if (h2) r1 = g2[t2];
        acc_rec(r0.x, lds, base, rlen);
        acc_rec(r0.y, lds, base, rlen);
        if (h2) { acc_rec(r1.x, lds, base, rlen); acc_rec(r1.y, lds, base, rlen); }
    }
    for (int t = (npair << 1) + (int)threadIdx.x; t < cnt; t += 512)
        acc_rec(g[t], lds, base, rlen);
    __syncthreads();

    float* __restrict__ cpy = copies + (size_t)b * n_nodes + base;
    for (int t = threadIdx.x; t < rlen; t += 512) cpy[t] = lds[t];
}

__global__ void __launch_bounds__(256)
reduce_copies_kernel(const float* __restrict__ copies, float* __restrict__ out,
                     int n_nodes) {
    const int k = blockIdx.x * blockDim.x + threadIdx.x;
    const int nvec = n_nodes >> 2;
    if (k < nvec) {
        vfloat4 v = {0.f, 0.f, 0.f, 0.f};
        for (int b = 0; b < SLICES; ++b)
            v += ((const vfloat4*)(copies + (size_t)b * n_nodes))[k];
        ((vfloat4*)out)[k] = v;
    } else if (k == nvec) {
        for (int i = nvec << 2; i < n_nodes; ++i) {
            float v = 0.0f;
            for (int b = 0; b < SLICES; ++b) v += copies[(size_t)b * n_nodes + i];
            out[i] = v;
        }
    }
}

// Fallback (shape/ws mismatch): direct device-scope atomics into d_out.
__global__ void __launch_bounds__(256)
conduction_edge_direct(const float* __restrict__ T, const float* __restrict__ cp,
                       const float* __restrict__ L, const float* __restrict__ cond,
                       const float* __restrict__ A, const float* __restrict__ time_step,
                       const int* __restrict__ src, const int* __restrict__ dst,
                       float* __restrict__ out, int n_edges) {
    int i = blockIdx.x * blockDim.x + threadIdx.x;
    if (i >= n_edges) return;
    const int s = src[i], d = dst[i];
    float delta = T[s] - T[d];
    if (delta <= 0.0f) return;
    const float dt = time_step[0];
    const float x = (delta / L[i]) * cond[i];
    const float e_cond = cbrtf(x) * A[i] * dt;
    const float cs = cp[s], cd = cp[d];
    const float max_e = delta * (cd * cs) / (cd + cs);
    const float Et = fminf(e_cond, max_e);
    atomicAdd(&out[d],  Et);
    atomicAdd(&out[s], -Et);
}

extern "C" void kernel_launch(void* const* d_in, const int* in_sizes, int n_in,
                              void* d_out, int out_size, void* d_ws, size_t ws_size,
                              hipStream_t stream) {
    const float* T    = (const float*)d_in[0];
    const float* cp   = (const float*)d_in[1];
    const float* L    = (const float*)d_in[2];
    const float* cond = (const float*)d_in[3];
    const float* A    = (const float*)d_in[4];
    const float* ts   = (const float*)d_in[5];
    const int*   src  = (const int*)d_in[6];
    const int*   dst  = (const int*)d_in[7];
    float* out = (float*)d_out;

    int n_nodes = in_sizes[0];
    int n_edges = in_sizes[2];

    const int block = 256;
    const int ngrid = (n_nodes + block - 1) / block;
    int R = (n_nodes + NRANGE - 1) / NRANGE;

    // chunk (edges/slice): multiple of WIN_E so windows never straddle slices
    int chunk = (n_edges + SLICES - 1) / SLICES;
    chunk = (chunk + WIN_E - 1) & ~(WIN_E - 1);
    int wps = chunk / WIN_E;                       // windows per slice
    int cap = (chunk >> 3) * 5;                    // 62.5% of chunk (~+80 sigma)

    const size_t tails_bytes = 256;                                // 64*4
    const size_t nodes_bytes = (size_t)n_nodes * sizeof(float2);
    const size_t recs_bytes  = (size_t)SLICES * cap * sizeof(u64);
    const size_t copy_bytes  = (size_t)SLICES * n_nodes * sizeof(float);
    const size_t need = tails_bytes + nodes_bytes + recs_bytes + copy_bytes;

    if (R <= RLEN_MAX && n_nodes <= (1 << 17) && ws_size >= need) {
        int*    tails  = (int*)d_ws;
        float2* nodes  = (float2*)((char*)d_ws + tails_bytes);
        u64*    recs   = (u64*)((char*)d_ws + tails_bytes + nodes_bytes);
        float*  copies = (float*)((char*)d_ws + tails_bytes + nodes_bytes + recs_bytes);

        void* kargs[] = {
            (void*)&T, (void*)&cp, (void*)&L, (void*)&cond, (void*)&A, (void*)&ts,
            (void*)&src, (void*)&dst, (void*)&nodes, (void*)&recs, (void*)&tails,
            (void*)&copies, (void*)&out,
            (void*)&n_nodes, (void*)&n_edges, (void*)&wps, (void*)&cap, (void*)&R };

        hipError_t err = hipLaunchCooperativeKernel(
            (const void*)fused_kernel, dim3(FB), dim3(FT), kargs, 0, stream);

        if (err != hipSuccess) {
            (void)hipGetLastError();               // clear; fall back to 4-dispatch
            pack_nodes_kernel<<<ngrid, block, 0, stream>>>(T, cp, nodes, tails, n_nodes);
            etrec_kernel<<<SLICES * wps, 512, 0, stream>>>(
                nodes, L, cond, A, ts, src, dst, recs, tails, n_edges, wps, cap);
            accrec_kernel<<<N_XCD * SL_XCD * NRANGE, 512, 0, stream>>>(
                recs, tails, copies, n_nodes, R, cap);
            const int rgrid = ((n_nodes >> 2) + 1 + block - 1) / block;
            reduce_copies_kernel<<<rgrid, block, 0, stream>>>(copies, out, n_nodes);
        }
    } else {
        (void)hipMemsetAsync(out, 0, (size_t)out_size * sizeof(float), stream);
        const int egrid = (n_edges + block - 1) / block;
        conduction_edge_direct<<<egrid, block, 0, stream>>>(
            T, cp, L, cond, A, ts, src, dst, out, n_edges);
    }
}

// Round 3
// 255.011 us; speedup vs baseline: 2.8060x; 2.8060x over previous
//
#include <hip/hip_runtime.h>
#include <hip/hip_bf16.h>
#include <hip/hip_fp16.h>

#define NRANGE   8       // node ranges (LDS accumulator tiles)
#define RLEN_MAX 12800   // floats per range in LDS (51.2 KB)
#define N_XCD    8       // MI355X XCDs; blockIdx%8 ~ XCD round-robin
#define SL_XCD   8       // slices per XCD
#define SLICES   64      // total edge slices (512 accrec blocks = 2/CU)
#define WIN_E    2048    // edges per etrec block (512 thr * 4)

typedef float vfloat4 __attribute__((ext_vector_type(4)));
typedef unsigned long long u64;

// Pack (T, cp) per node into float2; zero slice tails; zero out (accrec
// accumulates into out with device atomics — no reduce dispatch anymore).
__global__ void __launch_bounds__(256)
pack_nodes_kernel(const float* __restrict__ T, const float* __restrict__ cp,
                  float2* __restrict__ nodes, int* __restrict__ tails,
                  float* __restrict__ out, int n) {
    int i = blockIdx.x * blockDim.x + threadIdx.x;
    if (i < n) {
        nodes[i] = make_float2(T[i], cp[i]);
        out[i] = 0.0f;
    }
    if (blockIdx.x == 0 && threadIdx.x < SLICES) tails[threadIdx.x] = 0;
}

__device__ __forceinline__ float edge_e(float2 ns, float2 nd, float Li,
                                        float ci, float Ai, float dt) {
    const float delta = ns.x - nd.x;
    if (delta <= 0.0f) return 0.0f;
    const float x = (delta / Li) * ci;
    const float ec = cbrtf(x) * Ai * dt;
    const float comb = (nd.y * ns.y) / (nd.y + ns.y);
    return fminf(ec, delta * comb);
}

// record = s(17b) | d(17b)<<17 | f16(e)<<34  (only nonzero edges recorded)
__device__ __forceinline__ u64 make_rec(int s, int d, float e) {
    return (u64)(unsigned)s | ((u64)(unsigned)d << 17)
         | ((u64)__half_as_ushort(__float2half_rn(e)) << 34);
}

// One block per 2048-edge window, XCD-swizzled so each slice's records are
// produced and consumed through the SAME XCD's L2. Ballot compaction into
// per-wave LDS segments (zero per-element atomics), ONE global atomic/block.
// etrec is at the divergent-gather hardware floor (~3.8 cy/request, ~80 us;
// invariant across implementations; R2's low-occupancy fused variant proved
// it is LATENCY-hiding-dependent too — needs its full block count). DO NOT
// re-attack, do not reduce its resident-wave count.
__global__ void __launch_bounds__(512)
etrec_kernel(const float2* __restrict__ nodes,
             const float* __restrict__ L,
             const float* __restrict__ cond,
             const float* __restrict__ A,
             const float* __restrict__ time_step,
             const int* __restrict__ src,
             const int* __restrict__ dst,
             u64* __restrict__ recs,      // [SLICES][cap]
             int* __restrict__ tails,     // [SLICES]
             int n_edges, int wps, int cap) {
    __shared__ u64 srec[8 * 256];        // 8 waves x 256 records, 16 KB
    __shared__ int wcnt[8];
    __shared__ int wbase[8];
    __shared__ int sbase;

    const int wpx  = SL_XCD * wps;                        // windows per xcd
    const int w    = (blockIdx.x % N_XCD) * wpx + blockIdx.x / N_XCD;
    const int s    = w / wps;                             // slice of this window
    const int e0   = w * WIN_E;
    const int wave = threadIdx.x >> 6;
    const int lane = threadIdx.x & 63;

    int my_off = 0;                                       // wave-local count
    const bool active = (e0 < n_edges);

    if (active) {
        const float dt = time_step[0];
        float ev[4]; int sv[4]; int dv[4];

        if (e0 + WIN_E <= n_edges) {                      // full window: vec4
            const int kk = (e0 >> 2) + threadIdx.x;       // e0 % 4 == 0
            const int4    si = ((const int4*)src)[kk];
            const int4    di = ((const int4*)dst)[kk];
            const vfloat4 Lv = __builtin_nontemporal_load(&((const vfloat4*)L)[kk]);
            const vfloat4 cv = __builtin_nontemporal_load(&((const vfloat4*)cond)[kk]);
            const vfloat4 Av = __builtin_nontemporal_load(&((const vfloat4*)A)[kk]);
            const float2 ns0 = nodes[si.x], ns1 = nodes[si.y], ns2 = nodes[si.z], ns3 = nodes[si.w];
            const float2 nd0 = nodes[di.x], nd1 = nodes[di.y], nd2 = nodes[di.z], nd3 = nodes[di.w];
            ev[0] = edge_e(ns0, nd0, Lv.x, cv.x, Av.x, dt);
            ev[1] = edge_e(ns1, nd1, Lv.y, cv.y, Av.y, dt);
            ev[2] = edge_e(ns2, nd2, Lv.z, cv.z, Av.z, dt);
            ev[3] = edge_e(ns3, nd3, Lv.w, cv.w, Av.w, dt);
            sv[0] = si.x; sv[1] = si.y; sv[2] = si.z; sv[3] = si.w;
            dv[0] = di.x; dv[1] = di.y; dv[2] = di.z; dv[3] = di.w;
        } else {                                          // partial last window
#pragma unroll
            for (int j = 0; j < 4; ++j) {
                const int i = e0 + 4 * (int)threadIdx.x + j;
                float e = 0.0f; int a = 0, b2 = 0;
                if (i < n_edges) {
                    a = src[i]; b2 = dst[i];
                    e = edge_e(nodes[a], nodes[b2], L[i], cond[i], A[i], dt);
                }
                ev[j] = e; sv[j] = a; dv[j] = b2;
            }
        }

#pragma unroll
        for (int j = 0; j < 4; ++j) {
            const u64 mask = __ballot(ev[j] > 0.0f);
            if (ev[j] > 0.0f) {
                const int pos = my_off + __popcll(mask & ((1ull << lane) - 1ull));
                srec[(wave << 8) + pos] = make_rec(sv[j], dv[j], ev[j]);
            }
            my_off += (int)__popcll(mask);
        }
    }

    if (lane == 0) wcnt[wave] = my_off;
    __syncthreads();
    if (threadIdx.x == 0) {
        int tot = 0;
#pragma unroll
        for (int i = 0; i < 8; ++i) { wbase[i] = tot; tot += wcnt[i]; }
        sbase = (tot > 0) ? atomicAdd(&tails[s], tot) : 0;  // ONE atomic/block
    }
    __syncthreads();

    if (active) {
        const int c  = wcnt[wave];
        const int gb = sbase + wbase[wave];
        u64* __restrict__ dp = recs + (size_t)s * cap;
        for (int t = lane; t < c; t += 64) {
            const int p = gb + t;
            if (p < cap) dp[p] = srec[(wave << 8) + t];
        }
    }
}

__device__ __forceinline__ void acc_rec(u64 rec, float* __restrict__ lds,
                                        int base, int rlen) {
    const int   sv = (int)(rec & 0x1FFFF);
    const int   dv = (int)((rec >> 17) & 0x1FFFF);
    const float e  = __half2float(__ushort_as_half((unsigned short)(rec >> 34)));
    const int ls = sv - base; if ((unsigned)ls < (unsigned)rlen) atomicAdd(&lds[ls], -e);
    const int ld = dv - base; if ((unsigned)ld < (unsigned)rlen) atomicAdd(&lds[ld],  e);
}

// Block (r,b) XCD-swizzled; scans slice b's compacted records (8B/nonzero
// edge, XCD-L2-resident across the 8 range re-reads). Scan: 2 independent
// 16B loads (4 records) per step — MLP, since grid caps us at 2 blocks/CU.
// R3 change: epilogue accumulates STRAIGHT into out with predicated,
// per-wave-coalesced device atomicAdd — removes the copies spill (25.6 MB
// write + 25.6 MB re-read) and the entire reduce dispatch.
__global__ void __launch_bounds__(512)
accrec_kernel(const u64* __restrict__ recs,
              const int* __restrict__ tails,
              float* __restrict__ out,      // [n_nodes], pre-zeroed by pack
              int n_nodes, int R, int cap) {
    __shared__ float lds[RLEN_MAX];
    const int xcd = blockIdx.x % N_XCD;
    const int j   = blockIdx.x / N_XCD;
    const int r   = j % NRANGE;
    const int b   = xcd * SL_XCD + j / NRANGE;
    const int base = r * R;
    const int rlen = min(R, n_nodes - base);
    if (rlen <= 0) return;

    for (int t = threadIdx.x; t < rlen; t += 512) lds[t] = 0.0f;
    __syncthreads();

    const int cnt = min(tails[b], cap);
    const u64* __restrict__ g = recs + (size_t)b * cap;   // cap*8B: 16B-aligned
    const int npair = cnt >> 1;
    const ulonglong2* __restrict__ g2 = (const ulonglong2*)g;
    for (int t = threadIdx.x; t < npair; t += 1024) {
        const int t2 = t + 512;
        const bool h2 = (t2 < npair);
        // both loads issued before any use
        const ulonglong2 r0 = g2[t];
        ulonglong2 r1;
        if (h2) r1 = g2[t2];
        acc_rec(r0.x, lds, base, rlen);
        acc_rec(r0.y, lds, base, rlen);
        if (h2) {
            acc_rec(r1.x, lds, base, rlen);
            acc_rec(r1.y, lds, base, rlen);
        }
    }
    // odd tail record
    for (int t = (npair << 1) + (int)threadIdx.x; t < cnt; t += 512)
        acc_rec(g[t], lds, base, rlen);
    __syncthreads();

    // Direct accumulation: consecutive lanes -> consecutive addresses, so the
    // atomics line-coalesce at L2. Skip exact zeros (untouched slots, ~1/3).
    float* __restrict__ op = out + base;
    for (int t = threadIdx.x; t < rlen; t += 512) {
        const float v = lds[t];
        if (v != 0.0f) atomicAdd(&op[t], v);
    }
}

// Fallback (shape/ws mismatch): direct device-scope atomics into d_out.
__global__ void __launch_bounds__(256)
conduction_edge_direct(const float* __restrict__ T, const float* __restrict__ cp,
                       const float* __restrict__ L, const float* __restrict__ cond,
                       const float* __restrict__ A, const float* __restrict__ time_step,
                       const int* __restrict__ src, const int* __restrict__ dst,
                       float* __restrict__ out, int n_edges) {
    int i = blockIdx.x * blockDim.x + threadIdx.x;
    if (i >= n_edges) return;
    const int s = src[i], d = dst[i];
    float delta = T[s] - T[d];
    if (delta <= 0.0f) return;
    const float dt = time_step[0];
    const float x = (delta / L[i]) * cond[i];
    const float e_cond = cbrtf(x) * A[i] * dt;
    const float cs = cp[s], cd = cp[d];
    const float max_e = delta * (cd * cs) / (cd + cs);
    const float Et = fminf(e_cond, max_e);
    atomicAdd(&out[d],  Et);
    atomicAdd(&out[s], -Et);
}

extern "C" void kernel_launch(void* const* d_in, const int* in_sizes, int n_in,
                              void* d_out, int out_size, void* d_ws, size_t ws_size,
                              hipStream_t stream) {
    const float* T    = (const float*)d_in[0];
    const float* cp   = (const float*)d_in[1];
    const float* L    = (const float*)d_in[2];
    const float* cond = (const float*)d_in[3];
    const float* A    = (const float*)d_in[4];
    const float* ts   = (const float*)d_in[5];
    const int*   src  = (const int*)d_in[6];
    const int*   dst  = (const int*)d_in[7];
    float* out = (float*)d_out;

    const int n_nodes = in_sizes[0];
    const int n_edges = in_sizes[2];

    const int block = 256;
    const int ngrid = (n_nodes + block - 1) / block;
    const int R = (n_nodes + NRANGE - 1) / NRANGE;

    // chunk (edges/slice): multiple of WIN_E so windows never straddle slices
    int chunk = (n_edges + SLICES - 1) / SLICES;
    chunk = (chunk + WIN_E - 1) & ~(WIN_E - 1);
    const int wps = chunk / WIN_E;                 // windows per slice
    const int cap = (chunk >> 3) * 5;              // 62.5% of chunk (~+80 sigma)

    const size_t tails_bytes = 256;                                // 64*4
    const size_t nodes_bytes = (size_t)n_nodes * sizeof(float2);
    const size_t recs_bytes  = (size_t)SLICES * cap * sizeof(u64);
    const size_t need = tails_bytes + nodes_bytes + recs_bytes;

    if (R <= RLEN_MAX && n_nodes <= (1 << 17) && ws_size >= need) {
        int*    tails  = (int*)d_ws;
        float2* nodes  = (float2*)((char*)d_ws + tails_bytes);
        u64*    recs   = (u64*)((char*)d_ws + tails_bytes + nodes_bytes);

        pack_nodes_kernel<<<ngrid, block, 0, stream>>>(T, cp, nodes, tails, out, n_nodes);
        etrec_kernel<<<SLICES * wps, 512, 0, stream>>>(
            nodes, L, cond, A, ts, src, dst, recs, tails, n_edges, wps, cap);
        accrec_kernel<<<N_XCD * SL_XCD * NRANGE, 512, 0, stream>>>(
            recs, tails, out, n_nodes, R, cap);
    } else {
        (void)hipMemsetAsync(out, 0, (size_t)out_size * sizeof(float), stream);
        const int egrid = (n_edges + block - 1) / block;
        conduction_edge_direct<<<egrid, block, 0, stream>>>(
            T, cp, L, cond, A, ts, src, dst, out, n_edges);
    }
}

// Round 4
// 242.144 us; speedup vs baseline: 2.9551x; 1.0531x over previous
//
#include <hip/hip_runtime.h>
#include <hip/hip_bf16.h>
#include <hip/hip_fp16.h>

#define NRANGE   8       // node ranges (LDS accumulator tiles)
#define RLEN_MAX 12800   // floats per range in LDS (51.2 KB)
#define N_XCD    8       // MI355X XCDs; blockIdx%8 ~ XCD round-robin
#define SL_XCD   8       // slices per XCD
#define SLICES   64      // total edge slices (512 accrec blocks = 2/CU)
#define WIN_E    2048    // edges per etrec block (512 thr * 4)

typedef float vfloat4 __attribute__((ext_vector_type(4)));
typedef unsigned long long u64;

// Pack (T, cp) per node into float2; also zero the slice tails.
__global__ void __launch_bounds__(256)
pack_nodes_kernel(const float* __restrict__ T, const float* __restrict__ cp,
                  float2* __restrict__ nodes, int* __restrict__ tails, int n) {
    int i = blockIdx.x * blockDim.x + threadIdx.x;
    if (i < n) nodes[i] = make_float2(T[i], cp[i]);
    if (blockIdx.x == 0 && threadIdx.x < SLICES) tails[threadIdx.x] = 0;
}

__device__ __forceinline__ float edge_e(float2 ns, float2 nd, float Li,
                                        float ci, float Ai, float dt) {
    const float delta = ns.x - nd.x;
    if (delta <= 0.0f) return 0.0f;
    const float x = (delta / Li) * ci;
    const float ec = cbrtf(x) * Ai * dt;
    const float comb = (nd.y * ns.y) / (nd.y + ns.y);
    return fminf(ec, delta * comb);
}

// record = s(17b) | d(17b)<<17 | f16(e)<<34  (only nonzero edges recorded)
__device__ __forceinline__ u64 make_rec(int s, int d, float e) {
    return (u64)(unsigned)s | ((u64)(unsigned)d << 17)
         | ((u64)__half_as_ushort(__float2half_rn(e)) << 34);
}

// One block per 2048-edge window, XCD-swizzled so each slice's records are
// produced and consumed through the SAME XCD's L2. Ballot compaction into
// per-wave LDS segments (zero per-element atomics), ONE global atomic/block.
// etrec is at the divergent-gather hardware floor (~3.8 cy/request, ~80 us;
// invariant across 4 implementations incl. R2's occupancy-starved fused
// variant which proved it also needs full resident-wave count) — frozen.
__global__ void __launch_bounds__(512)
etrec_kernel(const float2* __restrict__ nodes,
             const float* __restrict__ L,
             const float* __restrict__ cond,
             const float* __restrict__ A,
             const float* __restrict__ time_step,
             const int* __restrict__ src,
             const int* __restrict__ dst,
             u64* __restrict__ recs,      // [SLICES][cap]
             int* __restrict__ tails,     // [SLICES]
             int n_edges, int wps, int cap) {
    __shared__ u64 srec[8 * 256];        // 8 waves x 256 records, 16 KB
    __shared__ int wcnt[8];
    __shared__ int wbase[8];
    __shared__ int sbase;

    const int wpx  = SL_XCD * wps;                        // windows per xcd
    const int w    = (blockIdx.x % N_XCD) * wpx + blockIdx.x / N_XCD;
    const int s    = w / wps;                             // slice of this window
    const int e0   = w * WIN_E;
    const int wave = threadIdx.x >> 6;
    const int lane = threadIdx.x & 63;

    int my_off = 0;                                       // wave-local count
    const bool active = (e0 < n_edges);

    if (active) {
        const float dt = time_step[0];
        float ev[4]; int sv[4]; int dv[4];

        if (e0 + WIN_E <= n_edges) {                      // full window: vec4
            const int kk = (e0 >> 2) + threadIdx.x;       // e0 % 4 == 0
            const int4    si = ((const int4*)src)[kk];
            const int4    di = ((const int4*)dst)[kk];
            const vfloat4 Lv = __builtin_nontemporal_load(&((const vfloat4*)L)[kk]);
            const vfloat4 cv = __builtin_nontemporal_load(&((const vfloat4*)cond)[kk]);
            const vfloat4 Av = __builtin_nontemporal_load(&((const vfloat4*)A)[kk]);
            const float2 ns0 = nodes[si.x], ns1 = nodes[si.y], ns2 = nodes[si.z], ns3 = nodes[si.w];
            const float2 nd0 = nodes[di.x], nd1 = nodes[di.y], nd2 = nodes[di.z], nd3 = nodes[di.w];
            ev[0] = edge_e(ns0, nd0, Lv.x, cv.x, Av.x, dt);
            ev[1] = edge_e(ns1, nd1, Lv.y, cv.y, Av.y, dt);
            ev[2] = edge_e(ns2, nd2, Lv.z, cv.z, Av.z, dt);
            ev[3] = edge_e(ns3, nd3, Lv.w, cv.w, Av.w, dt);
            sv[0] = si.x; sv[1] = si.y; sv[2] = si.z; sv[3] = si.w;
            dv[0] = di.x; dv[1] = di.y; dv[2] = di.z; dv[3] = di.w;
        } else {                                          // partial last window
#pragma unroll
            for (int j = 0; j < 4; ++j) {
                const int i = e0 + 4 * (int)threadIdx.x + j;
                float e = 0.0f; int a = 0, b2 = 0;
                if (i < n_edges) {
                    a = src[i]; b2 = dst[i];
                    e = edge_e(nodes[a], nodes[b2], L[i], cond[i], A[i], dt);
                }
                ev[j] = e; sv[j] = a; dv[j] = b2;
            }
        }

#pragma unroll
        for (int j = 0; j < 4; ++j) {
            const u64 mask = __ballot(ev[j] > 0.0f);
            if (ev[j] > 0.0f) {
                const int pos = my_off + __popcll(mask & ((1ull << lane) - 1ull));
                srec[(wave << 8) + pos] = make_rec(sv[j], dv[j], ev[j]);
            }
            my_off += (int)__popcll(mask);
        }
    }

    if (lane == 0) wcnt[wave] = my_off;
    __syncthreads();
    if (threadIdx.x == 0) {
        int tot = 0;
#pragma unroll
        for (int i = 0; i < 8; ++i) { wbase[i] = tot; tot += wcnt[i]; }
        sbase = (tot > 0) ? atomicAdd(&tails[s], tot) : 0;  // ONE atomic/block
    }
    __syncthreads();

    if (active) {
        const int c  = wcnt[wave];
        const int gb = sbase + wbase[wave];
        u64* __restrict__ dp = recs + (size_t)s * cap;
        for (int t = lane; t < c; t += 64) {
            const int p = gb + t;
            if (p < cap) dp[p] = srec[(wave << 8) + t];
        }
    }
}

__device__ __forceinline__ void acc_rec(u64 rec, float* __restrict__ lds,
                                        int base, int rlen) {
    const int   sv = (int)(rec & 0x1FFFF);
    const int   dv = (int)((rec >> 17) & 0x1FFFF);
    const float e  = __half2float(__ushort_as_half((unsigned short)(rec >> 34)));
    const int ls = sv - base; if ((unsigned)ls < (unsigned)rlen) atomicAdd(&lds[ls], -e);
    const int ld = dv - base; if ((unsigned)ld < (unsigned)rlen) atomicAdd(&lds[ld],  e);
}

// Block (r,b) XCD-swizzled; scans slice b's compacted records (8B/nonzero
// edge, XCD-L2-resident across the 8 range re-reads). Scan: 2 independent
// 16B loads (4 records) per step — MLP, since grid caps us at 2 blocks/CU.
__global__ void __launch_bounds__(512)
accrec_kernel(const u64* __restrict__ recs,
              const int* __restrict__ tails,
              float* __restrict__ copies,   // [SLICES][n_nodes]
              int n_nodes, int R, int cap) {
    __shared__ float lds[RLEN_MAX];
    const int xcd = blockIdx.x % N_XCD;
    const int j   = blockIdx.x / N_XCD;
    const int r   = j % NRANGE;
    const int b   = xcd * SL_XCD + j / NRANGE;
    const int base = r * R;
    const int rlen = min(R, n_nodes - base);

    for (int t = threadIdx.x; t < rlen; t += 512) lds[t] = 0.0f;
    __syncthreads();

    const int cnt = min(tails[b], cap);
    const u64* __restrict__ g = recs + (size_t)b * cap;   // cap*8B: 16B-aligned
    const int npair = cnt >> 1;
    const ulonglong2* __restrict__ g2 = (const ulonglong2*)g;
    for (int t = threadIdx.x; t < npair; t += 1024) {
        const int t2 = t + 512;
        const bool h2 = (t2 < npair);
        // both loads issued before any use
        const ulonglong2 r0 = g2[t];
        ulonglong2 r1;
        if (h2) r1 = g2[t2];
        acc_rec(r0.x, lds, base, rlen);
        acc_rec(r0.y, lds, base, rlen);
        if (h2) {
            acc_rec(r1.x, lds, base, rlen);
            acc_rec(r1.y, lds, base, rlen);
        }
    }
    // odd tail record
    for (int t = (npair << 1) + (int)threadIdx.x; t < cnt; t += 512)
        acc_rec(g[t], lds, base, rlen);
    __syncthreads();

    // Exclusive region of copies[b]: plain coalesced stores (covers all rlen).
    float* __restrict__ cpy = copies + (size_t)b * n_nodes + base;
    for (int t = threadIdx.x; t < rlen; t += 512) cpy[t] = lds[t];
}

// out[i..i+3] = sum over the slices, float4-vectorized. Read-once stream:
// nontemporal loads + unroll-8 for MLP.
__global__ void __launch_bounds__(256)
reduce_copies_kernel(const float* __restrict__ copies, float* __restrict__ out,
                     int n_nodes) {
    const int k = blockIdx.x * blockDim.x + threadIdx.x;
    const int nvec = n_nodes >> 2;
    if (k < nvec) {
        vfloat4 v = {0.f, 0.f, 0.f, 0.f};
#pragma unroll 8
        for (int b = 0; b < SLICES; ++b)
            v += __builtin_nontemporal_load(&((const vfloat4*)(copies + (size_t)b * n_nodes))[k]);
        ((vfloat4*)out)[k] = v;
    } else if (k == nvec) {
        for (int i = nvec << 2; i < n_nodes; ++i) {
            float v = 0.0f;
            for (int b = 0; b < SLICES; ++b) v += copies[(size_t)b * n_nodes + i];
            out[i] = v;
        }
    }
}

// Fallback (shape/ws mismatch): direct device-scope atomics into d_out.
__global__ void __launch_bounds__(256)
conduction_edge_direct(const float* __restrict__ T, const float* __restrict__ cp,
                       const float* __restrict__ L, const float* __restrict__ cond,
                       const float* __restrict__ A, const float* __restrict__ time_step,
                       const int* __restrict__ src, const int* __restrict__ dst,
                       float* __restrict__ out, int n_edges) {
    int i = blockIdx.x * blockDim.x + threadIdx.x;
    if (i >= n_edges) return;
    const int s = src[i], d = dst[i];
    float delta = T[s] - T[d];
    if (delta <= 0.0f) return;
    const float dt = time_step[0];
    const float x = (delta / L[i]) * cond[i];
    const float e_cond = cbrtf(x) * A[i] * dt;
    const float cs = cp[s], cd = cp[d];
    const float max_e = delta * (cd * cs) / (cd + cs);
    const float Et = fminf(e_cond, max_e);
    atomicAdd(&out[d],  Et);
    atomicAdd(&out[s], -Et);
}

extern "C" void kernel_launch(void* const* d_in, const int* in_sizes, int n_in,
                              void* d_out, int out_size, void* d_ws, size_t ws_size,
                              hipStream_t stream) {
    const float* T    = (const float*)d_in[0];
    const float* cp   = (const float*)d_in[1];
    const float* L    = (const float*)d_in[2];
    const float* cond = (const float*)d_in[3];
    const float* A    = (const float*)d_in[4];
    const float* ts   = (const float*)d_in[5];
    const int*   src  = (const int*)d_in[6];
    const int*   dst  = (const int*)d_in[7];
    float* out = (float*)d_out;

    const int n_nodes = in_sizes[0];
    const int n_edges = in_sizes[2];

    const int block = 256;
    const int ngrid = (n_nodes + block - 1) / block;
    const int R = (n_nodes + NRANGE - 1) / NRANGE;

    // chunk (edges/slice): multiple of WIN_E so windows never straddle slices
    int chunk = (n_edges + SLICES - 1) / SLICES;
    chunk = (chunk + WIN_E - 1) & ~(WIN_E - 1);
    const int wps = chunk / WIN_E;                 // windows per slice
    const int cap = (chunk >> 3) * 5;              // 62.5% of chunk (~+80 sigma)

    const size_t tails_bytes = 256;                                // 64*4
    const size_t nodes_bytes = (size_t)n_nodes * sizeof(float2);
    const size_t recs_bytes  = (size_t)SLICES * cap * sizeof(u64);
    const size_t copy_bytes  = (size_t)SLICES * n_nodes * sizeof(float);
    const size_t need = tails_bytes + nodes_bytes + recs_bytes + copy_bytes;

    if (R <= RLEN_MAX && n_nodes <= (1 << 17) && ws_size >= need) {
        int*    tails  = (int*)d_ws;
        float2* nodes  = (float2*)((char*)d_ws + tails_bytes);
        u64*    recs   = (u64*)((char*)d_ws + tails_bytes + nodes_bytes);
        float*  copies = (float*)((char*)d_ws + tails_bytes + nodes_bytes + recs_bytes);

        pack_nodes_kernel<<<ngrid, block, 0, stream>>>(T, cp, nodes, tails, n_nodes);
        etrec_kernel<<<SLICES * wps, 512, 0, stream>>>(
            nodes, L, cond, A, ts, src, dst, recs, tails, n_edges, wps, cap);
        accrec_kernel<<<N_XCD * SL_XCD * NRANGE, 512, 0, stream>>>(
            recs, tails, copies, n_nodes, R, cap);
        const int rgrid = ((n_nodes >> 2) + 1 + block - 1) / block;
        reduce_copies_kernel<<<rgrid, block, 0, stream>>>(copies, out, n_nodes);
    } else {
        (void)hipMemsetAsync(out, 0, (size_t)out_size * sizeof(float), stream);
        const int egrid = (n_edges + block - 1) / block;
        conduction_edge_direct<<<egrid, block, 0, stream>>>(
            T, cp, L, cond, A, ts, src, dst, out, n_edges);
    }
}